// Round 3
// baseline (522.755 us; speedup 1.0000x reference)
//
#include <hip/hip_runtime.h>

// Problem: xs (T=32768, 1, D=2048) fp32.
//   ys    = xs + 1                (T*D fp32, first in d_out)
//   carry = sum_t (xs[t]+1)       (D fp32, appended after ys in d_out)
// Pure streaming: 256 MiB read + 256 MiB write -> HBM-bound, ~85-90 us ideal.
//
// R2: 1024 blocks -> 31% occupancy, 2.5 TB/s, latency-bound (VGPR=32, few
// loads in flight). R3: 2048 blocks (100% wave capacity), 4-row load batches
// for ILP, nontemporal stores for the write-once ys stream.

constexpr int T = 32768;
constexpr int D = 2048;
constexpr int D4 = D / 4;                    // 512 float4 per row
constexpr int BLOCK = 256;                   // threads per block
constexpr int NBLOCKS = 2048;                // 8 blocks/CU -> 32 waves/CU
constexpr int ROWS_PER_BLOCK = T / NBLOCKS;  // 16

typedef float f32x4 __attribute__((ext_vector_type(4)));

__global__ __launch_bounds__(BLOCK)
void BiasAndSum_kernel(const f32x4* __restrict__ x,
                       f32x4* __restrict__ ys,
                       float* __restrict__ carry)
{
    const int t = threadIdx.x;                       // 0..255
    // Thread t owns float4 columns t and t+256 of every row in the strip.
    const long base = (long)blockIdx.x * ROWS_PER_BLOCK * D4 + t;

    f32x4 acc0 = {0.f, 0.f, 0.f, 0.f};
    f32x4 acc1 = {0.f, 0.f, 0.f, 0.f};

    // 4 batches of 4 rows: issue 8 loads, then 8 stores -> 8 vmem loads in
    // flight per thread, ~64 VGPR of load data.
    #pragma unroll
    for (int b = 0; b < ROWS_PER_BLOCK / 4; ++b) {
        f32x4 v[4][2];
        #pragma unroll
        for (int r = 0; r < 4; ++r) {
            const long idx = base + (long)(b * 4 + r) * D4;
            v[r][0] = x[idx];
            v[r][1] = x[idx + 256];
        }
        #pragma unroll
        for (int r = 0; r < 4; ++r) {
            const long idx = base + (long)(b * 4 + r) * D4;
            f32x4 v0 = v[r][0] + 1.f;
            f32x4 v1 = v[r][1] + 1.f;
            __builtin_nontemporal_store(v0, &ys[idx]);
            __builtin_nontemporal_store(v1, &ys[idx + 256]);
            acc0 += v0;
            acc1 += v1;
        }
    }

    // carry is zeroed by hipMemsetAsync before this kernel; device-scope atomics.
    float* c0 = carry + 4 * t;          // columns 4t..4t+3
    atomicAdd(c0 + 0, acc0.x);
    atomicAdd(c0 + 1, acc0.y);
    atomicAdd(c0 + 2, acc0.z);
    atomicAdd(c0 + 3, acc0.w);
    float* c1 = carry + 1024 + 4 * t;   // columns 1024+4t..1024+4t+3
    atomicAdd(c1 + 0, acc1.x);
    atomicAdd(c1 + 1, acc1.y);
    atomicAdd(c1 + 2, acc1.z);
    atomicAdd(c1 + 3, acc1.w);
}

extern "C" void kernel_launch(void* const* d_in, const int* in_sizes, int n_in,
                              void* d_out, int out_size, void* d_ws, size_t ws_size,
                              hipStream_t stream) {
    const float* x = (const float*)d_in[0];
    float* out = (float*)d_out;
    float* ys = out;                       // T*D elements
    float* carry = out + (size_t)T * D;    // D elements

    // Harness re-poisons d_out to 0xAA before every timed launch: zero the
    // carry tail (8 KB) so the atomic accumulation starts clean.
    hipMemsetAsync(carry, 0, D * sizeof(float), stream);

    BiasAndSum_kernel<<<NBLOCKS, BLOCK, 0, stream>>>(
        (const f32x4*)x, (f32x4*)ys, carry);
}